// Round 7
// baseline (68.087 us; speedup 1.0000x reference)
//
#include <hip/hip_runtime.h>

#define NB 32
#define NN 64
#define ND 128
#define NH 256
#define LN_EPS 1e-5f
#define RP 4

// ---- branchless erf-based GELU, A&S 7.1.25 (|erf err| <= 5e-4), Estrin form ----
// returns 2*gelu(x) = x*(1+erf(x/sqrt2)) ; caller folds the 0.5
__device__ __forceinline__ float gelu2(float x) {
    const float au  = fabsf(x);
    const float xpa = x + au;
    const float z   = au * 0.70710678118654752440f;
    const float z2  = z * z;
    const float pc  = fmaf(0.078108f, z, 0.000972f);   // c4 z + c3
    const float pb  = fmaf(0.278393f, z, 1.0f);        // c1 z + 1
    const float p   = fmaf(z2, fmaf(z, pc, 0.230389f), pb);
    const float p2  = p * p;
    const float r   = __builtin_amdgcn_rcpf(p2 * p2);  // p^-4 ; inf -> 0 (erf->1)
    return fmaf(-au, r, xpa);
}
__device__ __forceinline__ float gelu_h(float x) { return 0.5f * gelu2(x); }

// ---------------- K1 merged: [blocks 0..511] Pt/Qm/XW + rowstats ; [512..576] WC/v ----------------
__global__ __launch_bounds__(256) void k_pre(const float* __restrict__ slots,
                                             const float* __restrict__ We1,
                                             const float* __restrict__ be1,
                                             const float* __restrict__ Wn1,
                                             const float* __restrict__ We2,
                                             const float* __restrict__ be2,
                                             float* __restrict__ Pt,
                                             float* __restrict__ Qm,
                                             float* __restrict__ XW,
                                             float4* __restrict__ rowstats,
                                             float* __restrict__ WC,
                                             float* __restrict__ v) {
    __shared__ float xs[RP][ND];
    __shared__ float red[4][RP][4];
    const int t = threadIdx.x;

    if (blockIdx.x >= 512) {           // ---- prep role ----
        const int bid2 = blockIdx.x - 512;
        if (bid2 == 64) {              // v = be2 @ Wn1_bot
            __shared__ float bs[ND];
            if (t < ND) bs[t] = be2[t];
            __syncthreads();
            float acc = 0.f;
            #pragma unroll 4
            for (int d = 0; d < ND; ++d) acc = fmaf(bs[d], Wn1[(ND + d) * NH + t], acc);
            v[t] = acc;
            return;
        }
        const int k0 = bid2 * 4;       // WC rows k0..k0+3
        __shared__ float ws[4][ND];
        #pragma unroll
        for (int i = 0; i < 2; ++i) {
            const int idx = t + i * 256;
            ws[idx >> 7][idx & 127] = We2[(k0 + (idx >> 7)) * ND + (idx & 127)];
        }
        __syncthreads();
        float acc[4] = {0.f, 0.f, 0.f, 0.f};
        #pragma unroll 4
        for (int d = 0; d < ND; ++d) {
            const float wn = Wn1[(ND + d) * NH + t];
            #pragma unroll
            for (int r = 0; r < 4; ++r) acc[r] = fmaf(ws[r][d], wn, acc[r]);
        }
        #pragma unroll
        for (int r = 0; r < 4; ++r) WC[(k0 + r) * NH + t] = acc[r];
        return;
    }

    // ---- pq role ----
    const int r0 = blockIdx.x * RP;
    const int lane = t & 63, wave = t >> 6;
    #pragma unroll
    for (int i = 0; i < 2; ++i) {
        const int idx = t + i * 256;
        xs[idx >> 7][idx & 127] = slots[(size_t)(r0 + (idx >> 7)) * ND + (idx & 127)];
    }
    __syncthreads();
    float pt[RP], qq[RP], xw[RP];
    const float bb = be1[t];
    #pragma unroll
    for (int r = 0; r < RP; ++r) { pt[r] = bb; qq[r] = 0.f; xw[r] = 0.f; }
    #pragma unroll 8
    for (int d = 0; d < ND; ++d) {
        const float wt  = We1[d * NH + t];
        const float wbt = We1[(ND + d) * NH + t];
        const float wn  = Wn1[d * NH + t];
        #pragma unroll
        for (int r = 0; r < RP; ++r) {
            const float x = xs[r][d];
            pt[r] = fmaf(x, wt,  pt[r]);
            qq[r] = fmaf(x, wbt, qq[r]);
            xw[r] = fmaf(x, wn,  xw[r]);
        }
    }
    #pragma unroll
    for (int r = 0; r < RP; ++r) {
        const size_t row = (size_t)(r0 + r);
        Pt[row * NH + t] = pt[r];
        Qm[row * NH + t] = qq[r];
        XW[row * NH + t] = xw[r];
    }
    float s1[RP], s2[RP], s3[RP], s4[RP];
    #pragma unroll
    for (int r = 0; r < RP; ++r) {
        s1[r] = pt[r]; s2[r] = pt[r] * pt[r];
        s3[r] = qq[r]; s4[r] = qq[r] * qq[r];
    }
    #pragma unroll
    for (int off = 32; off; off >>= 1) {
        #pragma unroll
        for (int r = 0; r < RP; ++r) {
            s1[r] += __shfl_xor(s1[r], off);
            s2[r] += __shfl_xor(s2[r], off);
            s3[r] += __shfl_xor(s3[r], off);
            s4[r] += __shfl_xor(s4[r], off);
        }
    }
    if (lane == 0) {
        #pragma unroll
        for (int r = 0; r < RP; ++r) {
            red[wave][r][0] = s1[r]; red[wave][r][1] = s2[r];
            red[wave][r][2] = s3[r]; red[wave][r][3] = s4[r];
        }
    }
    __syncthreads();
    if (t < RP) {
        float4 st;
        st.x = (red[0][t][0] + red[1][t][0]) + (red[2][t][0] + red[3][t][0]);
        st.y = (red[0][t][1] + red[1][t][1]) + (red[2][t][1] + red[3][t][1]);
        st.z = (red[0][t][2] + red[1][t][2]) + (red[2][t][2] + red[3][t][2]);
        st.w = (red[0][t][3] + red[1][t][3]) + (red[2][t][3] + red[3][t][3]);
        rowstats[r0 + t] = st;
    }
}

// ---------------- K2: one row per block (2048 blocks, 8 blocks/CU) ----------------
__global__ __launch_bounds__(256, 8) void k_msg(
    const float* __restrict__ adj,
    const float* __restrict__ Pt,
    const float* __restrict__ Qm,
    const float4* __restrict__ rowstats,
    const float* __restrict__ ge,  const float* __restrict__ bge,
    float* __restrict__ Sw, float* __restrict__ wsumw)
{
    __shared__ float  lds_pt[NH];
    __shared__ float4 lds_wmr[NN];    // {0.5w, rr, -mu*rr, w}
    __shared__ float  lds_s[4][NH];

    const int row = blockIdx.x;       // b*NN + i
    const int b   = row >> 6;
    const int i   = row & 63;
    const int t   = threadIdx.x;
    const int lane = t & 63;
    const int wave = t >> 6;

    lds_pt[t] = Pt[(size_t)row * NH + t];
    __syncthreads();

    // C-dot: j = t>>2, part = t&3 (64 channels each)
    const int jp = t >> 2, part = t & 3;
    {
        float cd = 0.f;
        const float4* qrow = (const float4*)(Qm + ((size_t)b * NN + jp) * NH) + part * 16;
        const float4* pr   = (const float4*)lds_pt + part * 16;
        #pragma unroll 4
        for (int k = 0; k < 16; ++k) {
            const float4 q = qrow[k];
            const float4 p = pr[k];
            cd = fmaf(p.x, q.x, fmaf(p.y, q.y, fmaf(p.z, q.z, fmaf(p.w, q.w, cd))));
        }
        cd += __shfl_xor(cd, 1); cd += __shfl_xor(cd, 2);
        if (part == 0) {
            const float inv = 1.0f / NH;
            const float4 stj = rowstats[(size_t)b * NN + jp];
            const float4 sti = rowstats[row];
            float a = adj[(size_t)row * NN + jp];
            if (jp == i) a = 0.f;                     // diagonal mask
            const float mu = (sti.x + stj.z) * inv;
            const float e2 = fmaf(2.f, cd, sti.y + stj.w) * inv;
            const float rr = __builtin_amdgcn_rsqf(fmaf(-mu, mu, e2) + LN_EPS);
            lds_wmr[jp] = make_float4(0.5f * a, rr, -mu * rr, a);
        }
    }
    __syncthreads();

    if (wave == 0) {                  // wsum, off critical path
        float wv = lds_wmr[lane].w;
        #pragma unroll
        for (int off = 32; off; off >>= 1) wv += __shfl_xor(wv, off);
        if (lane == 0) wsumw[row] = wv;
    }

    // main loop: no cross-lane ops, no branches
    const float4 P  = ((const float4*)lds_pt)[lane];
    const float4 G  = ((const float4*)ge)[lane];
    const float4 Bg = ((const float4*)bge)[lane];
    const float4* Qb = (const float4*)(Qm + (size_t)b * NN * NH) + lane;
    float4 A = make_float4(0.f, 0.f, 0.f, 0.f);
    #pragma unroll 4
    for (int k = 0; k < 16; ++k) {
        const int jj = wave + 4 * k;
        const float4 q = Qb[jj * (NH / 4)];
        const float4 m = lds_wmr[jj];
        float h, u;
        h = P.x + q.x; u = fmaf(fmaf(h, m.y, m.z), G.x, Bg.x); A.x = fmaf(m.x, gelu2(u), A.x);
        h = P.y + q.y; u = fmaf(fmaf(h, m.y, m.z), G.y, Bg.y); A.y = fmaf(m.x, gelu2(u), A.y);
        h = P.z + q.z; u = fmaf(fmaf(h, m.y, m.z), G.z, Bg.z); A.z = fmaf(m.x, gelu2(u), A.z);
        h = P.w + q.w; u = fmaf(fmaf(h, m.y, m.z), G.w, Bg.w); A.w = fmaf(m.x, gelu2(u), A.w);
    }
    ((float4*)lds_s[wave])[lane] = A;
    __syncthreads();
    Sw[(size_t)row * NH + t] =
        (lds_s[0][t] + lds_s[1][t]) + (lds_s[2][t] + lds_s[3][t]);
}

// ---------------- K3: h1 = XW + S@WC + wsum*v + bn1 ; LN ; GELU ; out = x + g@Wn2 + bn2 ----------------
__global__ __launch_bounds__(512) void k_node(
    const float* __restrict__ slots,
    const float* __restrict__ Sw, const float* __restrict__ wsumw,
    const float* __restrict__ XW,
    const float* __restrict__ WC, const float* __restrict__ v,
    const float* __restrict__ bn1,
    const float* __restrict__ gn,  const float* __restrict__ bgn,
    const float* __restrict__ Wn2, const float* __restrict__ bn2,
    float* __restrict__ out)
{
    __shared__ float lds_S[4][NH];
    __shared__ float lds_part[4][NH];
    __shared__ float lds_g[4][NH];
    __shared__ float lds_d[4][4][ND];      // [row][ksplit][ch]
    __shared__ float lds_red[4][4][2];
    __shared__ float lds_mr[4][2];

    const int r0   = blockIdx.x * 4;
    const int t    = threadIdx.x;
    const int c    = t & 255;
    const int kh   = t >> 8;
    const int lane = t & 63;
    const int wave = t >> 6;

    lds_S[kh * 2 + 0][c] = Sw[(size_t)(r0 + kh * 2 + 0) * NH + c];
    lds_S[kh * 2 + 1][c] = Sw[(size_t)(r0 + kh * 2 + 1) * NH + c];
    __syncthreads();

    // phase A: partial S@WC over this half's k range
    float acc[4] = {0.f, 0.f, 0.f, 0.f};
    {
        const float* wc = WC + (size_t)kh * 128 * NH + c;
        #pragma unroll 16
        for (int k = 0; k < 128; ++k) {
            const float w = wc[k * NH];
            const int kk = kh * 128 + k;
            acc[0] = fmaf(lds_S[0][kk], w, acc[0]);
            acc[1] = fmaf(lds_S[1][kk], w, acc[1]);
            acc[2] = fmaf(lds_S[2][kk], w, acc[2]);
            acc[3] = fmaf(lds_S[3][kk], w, acc[3]);
        }
    }
    if (kh == 1) {
        #pragma unroll
        for (int r = 0; r < 4; ++r) lds_part[r][c] = acc[r];
    }
    __syncthreads();

    float h[4];
    if (kh == 0) {
        const float b1 = bn1[c], vc = v[c];
        #pragma unroll
        for (int r = 0; r < 4; ++r)
            h[r] = acc[r] + lds_part[r][c] + fmaf(wsumw[r0 + r], vc, b1)
                 + XW[(size_t)(r0 + r) * NH + c];
        float s1[4], s2[4];
        #pragma unroll
        for (int r = 0; r < 4; ++r) { s1[r] = h[r]; s2[r] = h[r] * h[r]; }
        #pragma unroll
        for (int off = 32; off; off >>= 1) {
            #pragma unroll
            for (int r = 0; r < 4; ++r) {
                s1[r] += __shfl_xor(s1[r], off);
                s2[r] += __shfl_xor(s2[r], off);
            }
        }
        if (lane == 0) {
            #pragma unroll
            for (int r = 0; r < 4; ++r) { lds_red[wave][r][0] = s1[r]; lds_red[wave][r][1] = s2[r]; }
        }
    }
    __syncthreads();
    if (t < 4) {
        const float S1 = (lds_red[0][t][0] + lds_red[1][t][0]) + (lds_red[2][t][0] + lds_red[3][t][0]);
        const float S2 = (lds_red[0][t][1] + lds_red[1][t][1]) + (lds_red[2][t][1] + lds_red[3][t][1]);
        const float mu  = S1 * (1.0f / NH);
        const float var = fmaf(-mu, mu, S2 * (1.0f / NH));
        lds_mr[t][0] = mu;
        lds_mr[t][1] = __builtin_amdgcn_rsqf(var + LN_EPS);
    }
    __syncthreads();
    if (kh == 0) {
        const float g = gn[c], bg = bgn[c];
        #pragma unroll
        for (int r = 0; r < 4; ++r) {
            const float rr = lds_mr[r][1];
            const float u0 = fmaf(h[r], rr, -lds_mr[r][0] * rr);
            lds_g[r][c] = gelu_h(fmaf(u0, g, bg));
        }
    }
    __syncthreads();

    // phase B: delta = g @ Wn2 + bn2, float4 loads with 4-way k-split
    {
        const int r  = t >> 7;          // row 0..3
        const int ks = (t >> 5) & 3;    // k-quarter 0..3
        const int cg = t & 31;          // channel group: channels 4cg..4cg+3
        float4 dacc = make_float4(0.f, 0.f, 0.f, 0.f);
        const float4* w2 = (const float4*)Wn2 + cg;
        const float*  gr = lds_g[r];
        const int kbeg = ks * 64;
        #pragma unroll 8
        for (int k = kbeg; k < kbeg + 64; ++k) {
            const float4 w = w2[k * (ND / 4)];
            const float gv = gr[k];
            dacc.x = fmaf(gv, w.x, dacc.x);
            dacc.y = fmaf(gv, w.y, dacc.y);
            dacc.z = fmaf(gv, w.z, dacc.z);
            dacc.w = fmaf(gv, w.w, dacc.w);
        }
        ((float4*)lds_d[r][ks])[cg] = dacc;
    }
    __syncthreads();
    {
        const int rg = t >> 7, c2 = t & 127;
        const float dsum = (lds_d[rg][0][c2] + lds_d[rg][1][c2])
                         + (lds_d[rg][2][c2] + lds_d[rg][3][c2]);
        const size_t o = (size_t)(r0 + rg) * ND + c2;
        out[o] = slots[o] + bn2[c2] + dsum;
    }
}

extern "C" void kernel_launch(void* const* d_in, const int* in_sizes, int n_in,
                              void* d_out, int out_size, void* d_ws, size_t ws_size,
                              hipStream_t stream) {
    const float* slots = (const float*)d_in[0];
    const float* adj   = (const float*)d_in[1];
    const float* We1   = (const float*)d_in[2];
    const float* be1   = (const float*)d_in[3];
    const float* ge    = (const float*)d_in[4];
    const float* bge   = (const float*)d_in[5];
    const float* We2   = (const float*)d_in[6];
    const float* be2   = (const float*)d_in[7];
    const float* Wn1   = (const float*)d_in[8];
    const float* bn1   = (const float*)d_in[9];
    const float* gn    = (const float*)d_in[10];
    const float* bgn   = (const float*)d_in[11];
    const float* Wn2   = (const float*)d_in[12];
    const float* bn2   = (const float*)d_in[13];
    float* out = (float*)d_out;

    const size_t RN = (size_t)NB * NN;      // 2048
    float*  Ptw   = (float*)d_ws;           // [2048,256]
    float*  Qw    = Ptw   + RN * NH;        // [2048,256]
    float*  XWw   = Qw    + RN * NH;        // [2048,256]
    float*  Sww   = XWw   + RN * NH;        // [2048,256]
    float*  wsumw = Sww   + RN * NH;        // [2048]
    float*  WCw   = wsumw + RN;             // [256,256]
    float*  vw    = WCw   + (size_t)NH * NH;// [256]
    float4* rsw   = (float4*)(vw + NH);     // [2048]

    k_pre <<<577,           256, 0, stream>>>(slots, We1, be1, Wn1, We2, be2,
                                              Ptw, Qw, XWw, rsw, WCw, vw);
    k_msg <<<(int)RN,       256, 0, stream>>>(adj, Ptw, Qw, rsw, ge, bge, Sww, wsumw);
    k_node<<<(int)(RN / 4), 512, 0, stream>>>(slots, Sww, wsumw, XWw, WCw, vw,
                                              bn1, gn, bgn, Wn2, bn2, out);
}

// Round 8
// 61.520 us; speedup vs baseline: 1.1067x; 1.1067x over previous
//
#include <hip/hip_runtime.h>

#define NB 32
#define NN 64
#define ND 128
#define NH 256
#define LN_EPS 1e-5f
#define RP 4

// ---- branchless erf-based GELU, A&S 7.1.25 (|erf err| <= 5e-4), Estrin form ----
// returns 2*gelu(x) = x*(1+erf(x/sqrt2)) ; caller folds the 0.5
__device__ __forceinline__ float gelu2(float x) {
    const float au  = fabsf(x);
    const float xpa = x + au;
    const float z   = au * 0.70710678118654752440f;
    const float z2  = z * z;
    const float pc  = fmaf(0.078108f, z, 0.000972f);   // c4 z + c3
    const float pb  = fmaf(0.278393f, z, 1.0f);        // c1 z + 1
    const float p   = fmaf(z2, fmaf(z, pc, 0.230389f), pb);
    const float p2  = p * p;
    const float r   = __builtin_amdgcn_rcpf(p2 * p2);  // p^-4 ; inf -> 0 (erf->1)
    return fmaf(-au, r, xpa);
}
__device__ __forceinline__ float gelu_h(float x) { return 0.5f * gelu2(x); }

// ---------------- K1 merged: [0..511] Pt/Qm/XW + rowstats ; [512..576] WC/v ----------------
__global__ __launch_bounds__(256) void k_pre(const float* __restrict__ slots,
                                             const float* __restrict__ We1,
                                             const float* __restrict__ be1,
                                             const float* __restrict__ Wn1,
                                             const float* __restrict__ We2,
                                             const float* __restrict__ be2,
                                             float* __restrict__ Pt,
                                             float* __restrict__ Qm,
                                             float* __restrict__ XW,
                                             float4* __restrict__ rowstats,
                                             float* __restrict__ WC,
                                             float* __restrict__ v) {
    __shared__ float xs[RP][ND];
    __shared__ float red[4][RP][4];
    const int t = threadIdx.x;

    if (blockIdx.x >= 512) {           // ---- prep role ----
        const int bid2 = blockIdx.x - 512;
        if (bid2 == 64) {              // v = be2 @ Wn1_bot
            __shared__ float bs[ND];
            if (t < ND) bs[t] = be2[t];
            __syncthreads();
            float acc = 0.f;
            #pragma unroll 4
            for (int d = 0; d < ND; ++d) acc = fmaf(bs[d], Wn1[(ND + d) * NH + t], acc);
            v[t] = acc;
            return;
        }
        const int k0 = bid2 * 4;       // WC rows k0..k0+3
        __shared__ float ws[4][ND];
        #pragma unroll
        for (int i = 0; i < 2; ++i) {
            const int idx = t + i * 256;
            ws[idx >> 7][idx & 127] = We2[(k0 + (idx >> 7)) * ND + (idx & 127)];
        }
        __syncthreads();
        float acc[4] = {0.f, 0.f, 0.f, 0.f};
        #pragma unroll 4
        for (int d = 0; d < ND; ++d) {
            const float wn = Wn1[(ND + d) * NH + t];
            #pragma unroll
            for (int r = 0; r < 4; ++r) acc[r] = fmaf(ws[r][d], wn, acc[r]);
        }
        #pragma unroll
        for (int r = 0; r < 4; ++r) WC[(k0 + r) * NH + t] = acc[r];
        return;
    }

    // ---- pq role ----
    const int r0 = blockIdx.x * RP;
    const int lane = t & 63, wave = t >> 6;
    #pragma unroll
    for (int i = 0; i < 2; ++i) {
        const int idx = t + i * 256;
        xs[idx >> 7][idx & 127] = slots[(size_t)(r0 + (idx >> 7)) * ND + (idx & 127)];
    }
    __syncthreads();
    float pt[RP], qq[RP], xw[RP];
    const float bb = be1[t];
    #pragma unroll
    for (int r = 0; r < RP; ++r) { pt[r] = bb; qq[r] = 0.f; xw[r] = 0.f; }
    #pragma unroll 4
    for (int d = 0; d < ND; ++d) {
        const float wt  = We1[d * NH + t];
        const float wbt = We1[(ND + d) * NH + t];
        const float wn  = Wn1[d * NH + t];
        #pragma unroll
        for (int r = 0; r < RP; ++r) {
            const float x = xs[r][d];
            pt[r] = fmaf(x, wt,  pt[r]);
            qq[r] = fmaf(x, wbt, qq[r]);
            xw[r] = fmaf(x, wn,  xw[r]);
        }
    }
    #pragma unroll
    for (int r = 0; r < RP; ++r) {
        const size_t row = (size_t)(r0 + r);
        Pt[row * NH + t] = pt[r];
        Qm[row * NH + t] = qq[r];
        XW[row * NH + t] = xw[r];
    }
    float s1[RP], s2[RP], s3[RP], s4[RP];
    #pragma unroll
    for (int r = 0; r < RP; ++r) {
        s1[r] = pt[r]; s2[r] = pt[r] * pt[r];
        s3[r] = qq[r]; s4[r] = qq[r] * qq[r];
    }
    #pragma unroll
    for (int off = 32; off; off >>= 1) {
        #pragma unroll
        for (int r = 0; r < RP; ++r) {
            s1[r] += __shfl_xor(s1[r], off);
            s2[r] += __shfl_xor(s2[r], off);
            s3[r] += __shfl_xor(s3[r], off);
            s4[r] += __shfl_xor(s4[r], off);
        }
    }
    if (lane == 0) {
        #pragma unroll
        for (int r = 0; r < RP; ++r) {
            red[wave][r][0] = s1[r]; red[wave][r][1] = s2[r];
            red[wave][r][2] = s3[r]; red[wave][r][3] = s4[r];
        }
    }
    __syncthreads();
    if (t < RP) {
        float4 st;
        st.x = (red[0][t][0] + red[1][t][0]) + (red[2][t][0] + red[3][t][0]);
        st.y = (red[0][t][1] + red[1][t][1]) + (red[2][t][1] + red[3][t][1]);
        st.z = (red[0][t][2] + red[1][t][2]) + (red[2][t][2] + red[3][t][2]);
        st.w = (red[0][t][3] + red[1][t][3]) + (red[2][t][3] + red[3][t][3]);
        rowstats[r0 + t] = st;
    }
}

// ---------------- K2: fused msg+node, 2 rows/block, 1024 blocks ----------------
__global__ __launch_bounds__(256, 8) void k_mn(
    const float* __restrict__ slots,
    const float* __restrict__ adj,
    const float* __restrict__ Pt,
    const float* __restrict__ Qm,
    const float4* __restrict__ rowstats,
    const float* __restrict__ ge,  const float* __restrict__ bge,
    const float* __restrict__ XW,
    const float* __restrict__ WC, const float* __restrict__ v,
    const float* __restrict__ bn1,
    const float* __restrict__ gn,  const float* __restrict__ bgn,
    const float* __restrict__ Wn2, const float* __restrict__ bn2,
    float* __restrict__ out)
{
    // phase-union: edge-phase buffers overlay node-phase buffers (12.25 KB total)
    union U {
        struct { float pt[2][NH]; float4 wmr[2][NN]; float s[4][2][NH]; } b; // 2+2+8 KB
        struct { float sf[2][NH]; float g[2][NH];    float d[2][8][ND]; } c; // 2+2+8 KB
    };
    __shared__ U u;
    __shared__ float lds_ws[2];
    __shared__ float lds_red[4][2][2];
    __shared__ float lds_mr[2][2];

    const int bid  = blockIdx.x;
    const int row0 = bid * 2;
    const int b    = row0 >> 6;
    const int i0   = row0 & 63;
    const int t    = threadIdx.x;
    const int lane = t & 63;
    const int wave = t >> 6;

    u.b.pt[0][t] = Pt[(size_t)row0 * NH + t];
    u.b.pt[1][t] = Pt[(size_t)(row0 + 1) * NH + t];
    __syncthreads();

    // ---- C-dot: j = t>>2, part = t&3 (64 channels each), both rows ----
    const int jp = t >> 2, part = t & 3;
    {
        float cd0 = 0.f, cd1 = 0.f;
        const float4* qrow = (const float4*)(Qm + ((size_t)b * NN + jp) * NH) + part * 16;
        const float4* p0   = (const float4*)u.b.pt[0] + part * 16;
        const float4* p1   = (const float4*)u.b.pt[1] + part * 16;
        #pragma unroll 4
        for (int k = 0; k < 16; ++k) {
            const float4 q = qrow[k];
            const float4 a = p0[k];
            const float4 c = p1[k];
            cd0 = fmaf(a.x, q.x, fmaf(a.y, q.y, fmaf(a.z, q.z, fmaf(a.w, q.w, cd0))));
            cd1 = fmaf(c.x, q.x, fmaf(c.y, q.y, fmaf(c.z, q.z, fmaf(c.w, q.w, cd1))));
        }
        cd0 += __shfl_xor(cd0, 1); cd0 += __shfl_xor(cd0, 2);
        cd1 += __shfl_xor(cd1, 1); cd1 += __shfl_xor(cd1, 2);
        if (part == 0) {
            const float inv = 1.0f / NH;
            const float4 stj = rowstats[(size_t)b * NN + jp];
            const float4 st0 = rowstats[row0];
            const float4 st1 = rowstats[row0 + 1];
            float a0 = adj[(size_t)row0 * NN + jp];       if (jp == i0)     a0 = 0.f;
            float a1 = adj[(size_t)(row0 + 1) * NN + jp]; if (jp == i0 + 1) a1 = 0.f;
            {
                const float mu = (st0.x + stj.z) * inv;
                const float e2 = fmaf(2.f, cd0, st0.y + stj.w) * inv;
                const float rr = __builtin_amdgcn_rsqf(fmaf(-mu, mu, e2) + LN_EPS);
                u.b.wmr[0][jp] = make_float4(0.5f * a0, rr, -mu * rr, a0);
            }
            {
                const float mu = (st1.x + stj.z) * inv;
                const float e2 = fmaf(2.f, cd1, st1.y + stj.w) * inv;
                const float rr = __builtin_amdgcn_rsqf(fmaf(-mu, mu, e2) + LN_EPS);
                u.b.wmr[1][jp] = make_float4(0.5f * a1, rr, -mu * rr, a1);
            }
        }
    }
    __syncthreads();

    if (wave < 2) {                    // wsum, off critical path
        float wv = u.b.wmr[wave][lane].w;
        #pragma unroll
        for (int off = 32; off; off >>= 1) wv += __shfl_xor(wv, off);
        if (lane == 0) lds_ws[wave] = wv;
    }

    // ---- edge main loop: no cross-lane ops, no branches ----
    const float4 P0 = ((const float4*)u.b.pt[0])[lane];
    const float4 P1 = ((const float4*)u.b.pt[1])[lane];
    const float4 G  = ((const float4*)ge)[lane];
    const float4 Bg = ((const float4*)bge)[lane];
    const float4* Qb = (const float4*)(Qm + (size_t)b * NN * NH) + lane;
    float4 A0 = make_float4(0.f, 0.f, 0.f, 0.f);
    float4 A1 = make_float4(0.f, 0.f, 0.f, 0.f);
    #pragma unroll 4
    for (int k = 0; k < 16; ++k) {
        const int jj = wave + 4 * k;
        const float4 q  = Qb[jj * (NH / 4)];
        const float4 m0 = u.b.wmr[0][jj];
        const float4 m1 = u.b.wmr[1][jj];
        float h, uu;
        h = P0.x + q.x; uu = fmaf(fmaf(h, m0.y, m0.z), G.x, Bg.x); A0.x = fmaf(m0.x, gelu2(uu), A0.x);
        h = P0.y + q.y; uu = fmaf(fmaf(h, m0.y, m0.z), G.y, Bg.y); A0.y = fmaf(m0.x, gelu2(uu), A0.y);
        h = P0.z + q.z; uu = fmaf(fmaf(h, m0.y, m0.z), G.z, Bg.z); A0.z = fmaf(m0.x, gelu2(uu), A0.z);
        h = P0.w + q.w; uu = fmaf(fmaf(h, m0.y, m0.z), G.w, Bg.w); A0.w = fmaf(m0.x, gelu2(uu), A0.w);
        h = P1.x + q.x; uu = fmaf(fmaf(h, m1.y, m1.z), G.x, Bg.x); A1.x = fmaf(m1.x, gelu2(uu), A1.x);
        h = P1.y + q.y; uu = fmaf(fmaf(h, m1.y, m1.z), G.y, Bg.y); A1.y = fmaf(m1.x, gelu2(uu), A1.y);
        h = P1.z + q.z; uu = fmaf(fmaf(h, m1.y, m1.z), G.z, Bg.z); A1.z = fmaf(m1.x, gelu2(uu), A1.z);
        h = P1.w + q.w; uu = fmaf(fmaf(h, m1.y, m1.z), G.w, Bg.w); A1.w = fmaf(m1.x, gelu2(uu), A1.w);
    }
    ((float4*)u.b.s[wave][0])[lane] = A0;
    ((float4*)u.b.s[wave][1])[lane] = A1;
    __syncthreads();

    // ---- reduce wave partials into sf (writes overlay dead pt region) ----
    const float sf0 = (u.b.s[0][0][t] + u.b.s[1][0][t]) + (u.b.s[2][0][t] + u.b.s[3][0][t]);
    const float sf1 = (u.b.s[0][1][t] + u.b.s[1][1][t]) + (u.b.s[2][1][t] + u.b.s[3][1][t]);
    __syncthreads();
    u.c.sf[0][t] = sf0;
    u.c.sf[1][t] = sf1;
    __syncthreads();

    // ---- node h1 = XW + S@WC + wsum*v + bn1 ----
    float a0, a1;
    {
        const float b1 = bn1[t], vc = v[t];
        a0 = fmaf(lds_ws[0], vc, b1) + XW[(size_t)row0 * NH + t];
        a1 = fmaf(lds_ws[1], vc, b1) + XW[(size_t)(row0 + 1) * NH + t];
        const float* wc = WC + t;
        #pragma unroll 8
        for (int k = 0; k < NH; ++k) {
            const float w = wc[k * NH];
            a0 = fmaf(u.c.sf[0][k], w, a0);
            a1 = fmaf(u.c.sf[1][k], w, a1);
        }
    }
    // ---- LN stats ----
    {
        float s1 = a0, s2 = a0 * a0, s3 = a1, s4 = a1 * a1;
        #pragma unroll
        for (int off = 32; off; off >>= 1) {
            s1 += __shfl_xor(s1, off); s2 += __shfl_xor(s2, off);
            s3 += __shfl_xor(s3, off); s4 += __shfl_xor(s4, off);
        }
        if (lane == 0) {
            lds_red[wave][0][0] = s1; lds_red[wave][0][1] = s2;
            lds_red[wave][1][0] = s3; lds_red[wave][1][1] = s4;
        }
    }
    __syncthreads();
    if (t < 2) {
        const float S1 = (lds_red[0][t][0] + lds_red[1][t][0]) + (lds_red[2][t][0] + lds_red[3][t][0]);
        const float S2 = (lds_red[0][t][1] + lds_red[1][t][1]) + (lds_red[2][t][1] + lds_red[3][t][1]);
        const float mu  = S1 * (1.0f / NH);
        const float var = fmaf(-mu, mu, S2 * (1.0f / NH));
        lds_mr[t][0] = mu;
        lds_mr[t][1] = __builtin_amdgcn_rsqf(var + LN_EPS);
    }
    __syncthreads();
    {
        const float g = gn[t], bg = bgn[t];
        const float rr0 = lds_mr[0][1], rr1 = lds_mr[1][1];
        u.c.g[0][t] = gelu_h(fmaf(fmaf(a0, rr0, -lds_mr[0][0] * rr0), g, bg));
        u.c.g[1][t] = gelu_h(fmaf(fmaf(a1, rr1, -lds_mr[1][0] * rr1), g, bg));
    }
    __syncthreads();

    // ---- delta = g @ Wn2 (float4 loads, 8-way k-split, both rows) ----
    {
        const int ks = t >> 5;          // 0..7
        const int cg = t & 31;          // channel group of 4
        float4 d0 = make_float4(0.f, 0.f, 0.f, 0.f);
        float4 d1 = make_float4(0.f, 0.f, 0.f, 0.f);
        const float4* w2 = (const float4*)Wn2 + cg;
        const int kbeg = ks * 32;
        #pragma unroll 8
        for (int k = kbeg; k < kbeg + 32; ++k) {
            const float4 w = w2[k * (ND / 4)];
            const float g0 = u.c.g[0][k];
            const float g1 = u.c.g[1][k];
            d0.x = fmaf(g0, w.x, d0.x); d0.y = fmaf(g0, w.y, d0.y);
            d0.z = fmaf(g0, w.z, d0.z); d0.w = fmaf(g0, w.w, d0.w);
            d1.x = fmaf(g1, w.x, d1.x); d1.y = fmaf(g1, w.y, d1.y);
            d1.z = fmaf(g1, w.z, d1.z); d1.w = fmaf(g1, w.w, d1.w);
        }
        ((float4*)u.c.d[0][ks])[cg] = d0;
        ((float4*)u.c.d[1][ks])[cg] = d1;
    }
    __syncthreads();
    {
        const int r  = t >> 7;          // 0..1
        const int c2 = t & 127;
        float ds = 0.f;
        #pragma unroll
        for (int p2 = 0; p2 < 8; ++p2) ds += u.c.d[r][p2][c2];
        const size_t o = (size_t)(row0 + r) * ND + c2;
        out[o] = slots[o] + bn2[c2] + ds;
    }
}

extern "C" void kernel_launch(void* const* d_in, const int* in_sizes, int n_in,
                              void* d_out, int out_size, void* d_ws, size_t ws_size,
                              hipStream_t stream) {
    const float* slots = (const float*)d_in[0];
    const float* adj   = (const float*)d_in[1];
    const float* We1   = (const float*)d_in[2];
    const float* be1   = (const float*)d_in[3];
    const float* ge    = (const float*)d_in[4];
    const float* bge   = (const float*)d_in[5];
    const float* We2   = (const float*)d_in[6];
    const float* be2   = (const float*)d_in[7];
    const float* Wn1   = (const float*)d_in[8];
    const float* bn1   = (const float*)d_in[9];
    const float* gn    = (const float*)d_in[10];
    const float* bgn   = (const float*)d_in[11];
    const float* Wn2   = (const float*)d_in[12];
    const float* bn2   = (const float*)d_in[13];
    float* out = (float*)d_out;

    const size_t RN = (size_t)NB * NN;      // 2048
    float*  Ptw   = (float*)d_ws;           // [2048,256]
    float*  Qw    = Ptw   + RN * NH;        // [2048,256]
    float*  XWw   = Qw    + RN * NH;        // [2048,256]
    float*  WCw   = XWw   + RN * NH;        // [256,256]
    float*  vw    = WCw   + (size_t)NH * NH;// [256]
    float4* rsw   = (float4*)(vw + NH);     // [2048]

    k_pre<<<577,       256, 0, stream>>>(slots, We1, be1, Wn1, We2, be2,
                                         Ptw, Qw, XWw, rsw, WCw, vw);
    k_mn <<<(int)(RN / 2), 256, 0, stream>>>(slots, adj, Ptw, Qw, rsw, ge, bge,
                                             XWw, WCw, vw, bn1, gn, bgn, Wn2, bn2, out);
}

// Round 9
// 56.978 us; speedup vs baseline: 1.1950x; 1.0797x over previous
//
#include <hip/hip_runtime.h>

#define NB 32
#define NN 64
#define ND 128
#define NH 256
#define LN_EPS 1e-5f
#define RP 4

typedef __attribute__((ext_vector_type(8))) short bf16x8;
typedef __attribute__((ext_vector_type(4))) float f32x4;

// ---- branchless erf-based GELU, A&S 7.1.25 (|erf err| <= 5e-4), Estrin form ----
__device__ __forceinline__ float gelu2(float x) {     // returns 2*gelu(x)
    const float au  = fabsf(x);
    const float xpa = x + au;
    const float z   = au * 0.70710678118654752440f;
    const float z2  = z * z;
    const float pc  = fmaf(0.078108f, z, 0.000972f);
    const float pb  = fmaf(0.278393f, z, 1.0f);
    const float p   = fmaf(z2, fmaf(z, pc, 0.230389f), pb);
    const float p2  = p * p;
    const float r   = __builtin_amdgcn_rcpf(p2 * p2);
    return fmaf(-au, r, xpa);
}
__device__ __forceinline__ float gelu_h(float x) { return 0.5f * gelu2(x); }

__device__ __forceinline__ short f2bf(float f) {      // RNE float->bf16
    unsigned u = __float_as_uint(f);
    u += 0x7FFFu + ((u >> 16) & 1u);
    return (short)(u >> 16);
}

// ---------------- K1: [0..511] Pt/Qm/XW/Pb/Qb + rowstats ; [512..576] WC/v ----------------
__global__ __launch_bounds__(256) void k_pre(const float* __restrict__ slots,
                                             const float* __restrict__ We1,
                                             const float* __restrict__ be1,
                                             const float* __restrict__ Wn1,
                                             const float* __restrict__ We2,
                                             const float* __restrict__ be2,
                                             float* __restrict__ Pt,
                                             float* __restrict__ Qm,
                                             float* __restrict__ XW,
                                             short* __restrict__ Pb,
                                             short* __restrict__ Qb,
                                             float4* __restrict__ rowstats,
                                             float* __restrict__ WC,
                                             float* __restrict__ v) {
    __shared__ float xs[RP][ND];
    __shared__ float red[4][RP][4];
    const int t = threadIdx.x;

    if (blockIdx.x >= 512) {           // ---- prep role ----
        const int bid2 = blockIdx.x - 512;
        if (bid2 == 64) {              // v = be2 @ Wn1_bot
            __shared__ float bs[ND];
            if (t < ND) bs[t] = be2[t];
            __syncthreads();
            float acc = 0.f;
            #pragma unroll 4
            for (int d = 0; d < ND; ++d) acc = fmaf(bs[d], Wn1[(ND + d) * NH + t], acc);
            v[t] = acc;
            return;
        }
        const int k0 = bid2 * 4;       // WC rows k0..k0+3
        __shared__ float ws[4][ND];
        #pragma unroll
        for (int i = 0; i < 2; ++i) {
            const int idx = t + i * 256;
            ws[idx >> 7][idx & 127] = We2[(k0 + (idx >> 7)) * ND + (idx & 127)];
        }
        __syncthreads();
        float acc[4] = {0.f, 0.f, 0.f, 0.f};
        #pragma unroll 4
        for (int d = 0; d < ND; ++d) {
            const float wn = Wn1[(ND + d) * NH + t];
            #pragma unroll
            for (int r = 0; r < 4; ++r) acc[r] = fmaf(ws[r][d], wn, acc[r]);
        }
        #pragma unroll
        for (int r = 0; r < 4; ++r) WC[(k0 + r) * NH + t] = acc[r];
        return;
    }

    // ---- pq role ----
    const int r0 = blockIdx.x * RP;
    const int lane = t & 63, wave = t >> 6;
    #pragma unroll
    for (int i = 0; i < 2; ++i) {
        const int idx = t + i * 256;
        xs[idx >> 7][idx & 127] = slots[(size_t)(r0 + (idx >> 7)) * ND + (idx & 127)];
    }
    __syncthreads();
    float pt[RP], qq[RP], xw[RP];
    const float bb = be1[t];
    #pragma unroll
    for (int r = 0; r < RP; ++r) { pt[r] = bb; qq[r] = 0.f; xw[r] = 0.f; }
    #pragma unroll 4
    for (int d = 0; d < ND; ++d) {
        const float wt  = We1[d * NH + t];
        const float wbt = We1[(ND + d) * NH + t];
        const float wn  = Wn1[d * NH + t];
        #pragma unroll
        for (int r = 0; r < RP; ++r) {
            const float x = xs[r][d];
            pt[r] = fmaf(x, wt,  pt[r]);
            qq[r] = fmaf(x, wbt, qq[r]);
            xw[r] = fmaf(x, wn,  xw[r]);
        }
    }
    #pragma unroll
    for (int r = 0; r < RP; ++r) {
        const size_t row = (size_t)(r0 + r);
        Pt[row * NH + t] = pt[r];
        Qm[row * NH + t] = qq[r];
        XW[row * NH + t] = xw[r];
        Pb[row * NH + t] = f2bf(pt[r]);
        Qb[row * NH + t] = f2bf(qq[r]);
    }
    float s1[RP], s2[RP], s3[RP], s4[RP];
    #pragma unroll
    for (int r = 0; r < RP; ++r) {
        s1[r] = pt[r]; s2[r] = pt[r] * pt[r];
        s3[r] = qq[r]; s4[r] = qq[r] * qq[r];
    }
    #pragma unroll
    for (int off = 32; off; off >>= 1) {
        #pragma unroll
        for (int r = 0; r < RP; ++r) {
            s1[r] += __shfl_xor(s1[r], off);
            s2[r] += __shfl_xor(s2[r], off);
            s3[r] += __shfl_xor(s3[r], off);
            s4[r] += __shfl_xor(s4[r], off);
        }
    }
    if (lane == 0) {
        #pragma unroll
        for (int r = 0; r < RP; ++r) {
            red[wave][r][0] = s1[r]; red[wave][r][1] = s2[r];
            red[wave][r][2] = s3[r]; red[wave][r][3] = s4[r];
        }
    }
    __syncthreads();
    if (t < RP) {
        float4 st;
        st.x = (red[0][t][0] + red[1][t][0]) + (red[2][t][0] + red[3][t][0]);
        st.y = (red[0][t][1] + red[1][t][1]) + (red[2][t][1] + red[3][t][1]);
        st.z = (red[0][t][2] + red[1][t][2]) + (red[2][t][2] + red[3][t][2]);
        st.w = (red[0][t][3] + red[1][t][3]) + (red[2][t][3] + red[3][t][3]);
        rowstats[r0 + t] = st;
    }
}

// ---------------- K2: MFMA dot -> wmr table {0.5w, rr, -mu*rr, w} ----------------
// block = (batch, j-tile); waves = 4 i-tiles of 16. D[i,j] = P_i . Q_j  (K=256)
__global__ __launch_bounds__(256) void k_dot(
    const short* __restrict__ Pb, const short* __restrict__ Qb,
    const float4* __restrict__ rowstats,
    const float* __restrict__ adj,
    float4* __restrict__ wmrG)
{
    const int b  = blockIdx.x >> 2;
    const int jt = blockIdx.x & 3;
    const int t  = threadIdx.x;
    const int l  = t & 63;
    const int i0 = (t >> 6) * 16;
    const int j0 = jt * 16;
    const int rA = l & 15;          // A row / B col within tile
    const int kg = l >> 4;          // k-group

    const short* Prow = Pb + ((size_t)b * NN + i0 + rA) * NH + kg * 8;
    const short* Qrow = Qb + ((size_t)b * NN + j0 + rA) * NH + kg * 8;
    f32x4 acc = {0.f, 0.f, 0.f, 0.f};
    #pragma unroll
    for (int kc = 0; kc < 8; ++kc) {
        const bf16x8 av = *(const bf16x8*)(Prow + kc * 32);
        const bf16x8 bv = *(const bf16x8*)(Qrow + kc * 32);
        acc = __builtin_amdgcn_mfma_f32_16x16x32_bf16(av, bv, acc, 0, 0, 0);
    }
    // C/D: col = lane&15 (j), row = (lane>>4)*4 + q (i)   [m89-verified mapping]
    const int j  = j0 + (l & 15);
    const int gj = b * NN + j;
    const float4 stj = rowstats[gj];
    const float inv = 1.0f / NH;
    #pragma unroll
    for (int q = 0; q < 4; ++q) {
        const int i  = i0 + (l >> 4) * 4 + q;
        const int gi = b * NN + i;
        const float4 sti = rowstats[gi];
        float a = adj[(size_t)gi * NN + j];
        if (j == i) a = 0.f;
        const float cd = acc[q];
        const float mu = (sti.x + stj.z) * inv;
        const float e2 = fmaf(2.f, cd, sti.y + stj.w) * inv;
        const float rr = __builtin_amdgcn_rsqf(fmaf(-mu, mu, e2) + LN_EPS);
        wmrG[(size_t)gi * NN + j] = make_float4(0.5f * a, rr, -mu * rr, a);
    }
}

// ---------------- K3: fused msg+node, 2 rows/block, 1024 blocks ----------------
__global__ __launch_bounds__(256, 4) void k_mn(
    const float* __restrict__ slots,
    const float* __restrict__ Pt,
    const float* __restrict__ Qm,
    const float4* __restrict__ wmrG,
    const float* __restrict__ ge,  const float* __restrict__ bge,
    const float* __restrict__ XW,
    const float* __restrict__ WC, const float* __restrict__ v,
    const float* __restrict__ bn1,
    const float* __restrict__ gn,  const float* __restrict__ bgn,
    const float* __restrict__ Wn2, const float* __restrict__ bn2,
    float* __restrict__ out)
{
    union U {
        struct { float4 wmr[2][NN]; float s[4][2][NH]; } e;                  // 2K + 8K
        struct { float sfg[2][NH];
                 union { float part[2][4][NH]; float d[2][8][ND + 4]; } w; } n;
    };
    __shared__ U u;
    __shared__ float lds_ws[2];
    __shared__ float lds_red[4][2][2];
    __shared__ float lds_mr[2][2];

    const int row0 = blockIdx.x * 2;
    const int b    = row0 >> 6;
    const int t    = threadIdx.x;
    const int lane = t & 63;
    const int wave = t >> 6;

    // prefetch row-local globals
    const float xw0 = XW[(size_t)row0 * NH + t];
    const float xw1 = XW[(size_t)(row0 + 1) * NH + t];
    const float sl  = slots[(size_t)(row0 + (t >> 7)) * ND + (t & 127)];
    if (t < 128) {
        const int r = t >> 6, j = t & 63;
        u.e.wmr[r][j] = wmrG[(size_t)(row0 + r) * NN + j];
    }
    const float4 P0 = ((const float4*)(Pt + (size_t)row0 * NH))[lane];
    const float4 P1 = ((const float4*)(Pt + (size_t)(row0 + 1) * NH))[lane];
    const float4 G  = ((const float4*)ge)[lane];
    const float4 Bg = ((const float4*)bge)[lane];
    __syncthreads();                                   // bar1: wmr ready

    if (wave < 2) {                                    // wsum, off critical path
        float wv = u.e.wmr[wave][lane].w;
        #pragma unroll
        for (int off = 32; off; off >>= 1) wv += __shfl_xor(wv, off);
        if (lane == 0) lds_ws[wave] = wv;
    }

    // ---- edge main loop ----
    const float4* Qb4 = (const float4*)(Qm + (size_t)b * NN * NH) + lane;
    float4 A0 = make_float4(0.f, 0.f, 0.f, 0.f);
    float4 A1 = make_float4(0.f, 0.f, 0.f, 0.f);
    #pragma unroll 4
    for (int k = 0; k < 16; ++k) {
        const int jj = wave + 4 * k;
        const float4 q  = Qb4[jj * (NH / 4)];
        const float4 m0 = u.e.wmr[0][jj];
        const float4 m1 = u.e.wmr[1][jj];
        float h, uu;
        h = P0.x + q.x; uu = fmaf(fmaf(h, m0.y, m0.z), G.x, Bg.x); A0.x = fmaf(m0.x, gelu2(uu), A0.x);
        h = P0.y + q.y; uu = fmaf(fmaf(h, m0.y, m0.z), G.y, Bg.y); A0.y = fmaf(m0.x, gelu2(uu), A0.y);
        h = P0.z + q.z; uu = fmaf(fmaf(h, m0.y, m0.z), G.z, Bg.z); A0.z = fmaf(m0.x, gelu2(uu), A0.z);
        h = P0.w + q.w; uu = fmaf(fmaf(h, m0.y, m0.z), G.w, Bg.w); A0.w = fmaf(m0.x, gelu2(uu), A0.w);
        h = P1.x + q.x; uu = fmaf(fmaf(h, m1.y, m1.z), G.x, Bg.x); A1.x = fmaf(m1.x, gelu2(uu), A1.x);
        h = P1.y + q.y; uu = fmaf(fmaf(h, m1.y, m1.z), G.y, Bg.y); A1.y = fmaf(m1.x, gelu2(uu), A1.y);
        h = P1.z + q.z; uu = fmaf(fmaf(h, m1.y, m1.z), G.z, Bg.z); A1.z = fmaf(m1.x, gelu2(uu), A1.z);
        h = P1.w + q.w; uu = fmaf(fmaf(h, m1.y, m1.z), G.w, Bg.w); A1.w = fmaf(m1.x, gelu2(uu), A1.w);
    }
    ((float4*)u.e.s[wave][0])[lane] = A0;
    ((float4*)u.e.s[wave][1])[lane] = A1;
    __syncthreads();                                   // bar2: s ready, wmr dead

    // ---- reduce wave partials into sfg (overlays wmr) ----
    const float sf0 = (u.e.s[0][0][t] + u.e.s[1][0][t]) + (u.e.s[2][0][t] + u.e.s[3][0][t]);
    const float sf1 = (u.e.s[0][1][t] + u.e.s[1][1][t]) + (u.e.s[2][1][t] + u.e.s[3][1][t]);
    u.n.sfg[0][t] = sf0;
    u.n.sfg[1][t] = sf1;
    __syncthreads();                                   // bar3: sfg ready, s dead

    // ---- WC GEMV: float4 loads, 4-way k-split ----
    {
        const int ks = wave;            // k range 64*ks..
        const int cg = lane;            // channels 4cg..4cg+3
        float4 h0 = make_float4(0.f, 0.f, 0.f, 0.f);
        float4 h1 = make_float4(0.f, 0.f, 0.f, 0.f);
        const float4* wc4 = (const float4*)WC + cg;
        #pragma unroll 8
        for (int k = ks * 64; k < ks * 64 + 64; ++k) {
            const float4 w = wc4[k * (NH / 4)];
            const float sa = u.n.sfg[0][k];
            const float sb = u.n.sfg[1][k];
            h0.x = fmaf(sa, w.x, h0.x); h0.y = fmaf(sa, w.y, h0.y);
            h0.z = fmaf(sa, w.z, h0.z); h0.w = fmaf(sa, w.w, h0.w);
            h1.x = fmaf(sb, w.x, h1.x); h1.y = fmaf(sb, w.y, h1.y);
            h1.z = fmaf(sb, w.z, h1.z); h1.w = fmaf(sb, w.w, h1.w);
        }
        ((float4*)u.n.w.part[0][ks])[cg] = h0;
        ((float4*)u.n.w.part[1][ks])[cg] = h1;
    }
    __syncthreads();                                   // bar4: part ready, sfg reads done

    // ---- h1 assemble + LN stats ----
    float a0, a1;
    {
        const float b1 = bn1[t], vc = v[t];
        a0 = (u.n.w.part[0][0][t] + u.n.w.part[0][1][t])
           + (u.n.w.part[0][2][t] + u.n.w.part[0][3][t])
           + fmaf(lds_ws[0], vc, b1) + xw0;
        a1 = (u.n.w.part[1][0][t] + u.n.w.part[1][1][t])
           + (u.n.w.part[1][2][t] + u.n.w.part[1][3][t])
           + fmaf(lds_ws[1], vc, b1) + xw1;
    }
    {
        float s1 = a0, s2 = a0 * a0, s3 = a1, s4 = a1 * a1;
        #pragma unroll
        for (int off = 32; off; off >>= 1) {
            s1 += __shfl_xor(s1, off); s2 += __shfl_xor(s2, off);
            s3 += __shfl_xor(s3, off); s4 += __shfl_xor(s4, off);
        }
        if (lane == 0) {
            lds_red[wave][0][0] = s1; lds_red[wave][0][1] = s2;
            lds_red[wave][1][0] = s3; lds_red[wave][1][1] = s4;
        }
    }
    __syncthreads();                                   // bar5: part reads done
    if (t < 2) {
        const float S1 = (lds_red[0][t][0] + lds_red[1][t][0]) + (lds_red[2][t][0] + lds_red[3][t][0]);
        const float S2 = (lds_red[0][t][1] + lds_red[1][t][1]) + (lds_red[2][t][1] + lds_red[3][t][1]);
        const float mu  = S1 * (1.0f / NH);
        const float var = fmaf(-mu, mu, S2 * (1.0f / NH));
        lds_mr[t][0] = mu;
        lds_mr[t][1] = __builtin_amdgcn_rsqf(var + LN_EPS);
    }
    __syncthreads();                                   // bar6
    {
        const float g = gn[t], bg = bgn[t];
        const float rr0 = lds_mr[0][1], rr1 = lds_mr[1][1];
        u.n.sfg[0][t] = gelu_h(fmaf(fmaf(a0, rr0, -lds_mr[0][0] * rr0), g, bg));
        u.n.sfg[1][t] = gelu_h(fmaf(fmaf(a1, rr1, -lds_mr[1][0] * rr1), g, bg));
    }
    __syncthreads();                                   // bar7: g ready

    // ---- delta = g @ Wn2 (float4 loads, 8-way k-split, both rows) ----
    {
        const int ks = t >> 5;          // 0..7
        const int cg = t & 31;          // channel group of 4
        float4 d0 = make_float4(0.f, 0.f, 0.f, 0.f);
        float4 d1 = make_float4(0.f, 0.f, 0.f, 0.f);
        const float4* w2 = (const float4*)Wn2 + cg;
        const int kbeg = ks * 32;
        #pragma unroll 8
        for (int k = kbeg; k < kbeg + 32; ++k) {
            const float4 w = w2[k * (ND / 4)];
            const float g0 = u.n.sfg[0][k];
            const float g1 = u.n.sfg[1][k];
            d0.x = fmaf(g0, w.x, d0.x); d0.y = fmaf(g0, w.y, d0.y);
            d0.z = fmaf(g0, w.z, d0.z); d0.w = fmaf(g0, w.w, d0.w);
            d1.x = fmaf(g1, w.x, d1.x); d1.y = fmaf(g1, w.y, d1.y);
            d1.z = fmaf(g1, w.z, d1.z); d1.w = fmaf(g1, w.w, d1.w);
        }
        ((float4*)u.n.w.d[0][ks])[cg] = d0;
        ((float4*)u.n.w.d[1][ks])[cg] = d1;
    }
    __syncthreads();                                   // bar8: d ready
    {
        const int r  = t >> 7;
        const int c2 = t & 127;
        float ds = 0.f;
        #pragma unroll
        for (int p2 = 0; p2 < 8; ++p2) ds += u.n.w.d[r][p2][c2];
        out[(size_t)(row0 + r) * ND + c2] = sl + bn2[c2] + ds;
    }
}

extern "C" void kernel_launch(void* const* d_in, const int* in_sizes, int n_in,
                              void* d_out, int out_size, void* d_ws, size_t ws_size,
                              hipStream_t stream) {
    const float* slots = (const float*)d_in[0];
    const float* adj   = (const float*)d_in[1];
    const float* We1   = (const float*)d_in[2];
    const float* be1   = (const float*)d_in[3];
    const float* ge    = (const float*)d_in[4];
    const float* bge   = (const float*)d_in[5];
    const float* We2   = (const float*)d_in[6];
    const float* be2   = (const float*)d_in[7];
    const float* Wn1   = (const float*)d_in[8];
    const float* bn1   = (const float*)d_in[9];
    const float* gn    = (const float*)d_in[10];
    const float* bgn   = (const float*)d_in[11];
    const float* Wn2   = (const float*)d_in[12];
    const float* bn2   = (const float*)d_in[13];
    float* out = (float*)d_out;

    const size_t RN = (size_t)NB * NN;       // 2048
    float*  Ptw  = (float*)d_ws;             // [2048,256]
    float*  Qw   = Ptw  + RN * NH;           // [2048,256]
    float*  XWw  = Qw   + RN * NH;           // [2048,256]
    float*  WCw  = XWw  + RN * NH;           // [256,256]
    float*  vw   = WCw  + (size_t)NH * NH;   // [256]
    float4* rsw  = (float4*)(vw + NH);       // [2048] 16B-aligned
    float4* wmrw = rsw + RN;                 // [2048*64]
    short*  Pbw  = (short*)(wmrw + RN * NN); // [2048,256] bf16
    short*  Qbw  = Pbw + RN * NH;            // [2048,256] bf16

    k_pre<<<577,           256, 0, stream>>>(slots, We1, be1, Wn1, We2, be2,
                                             Ptw, Qw, XWw, Pbw, Qbw, rsw, WCw, vw);
    k_dot<<<NB * 4,        256, 0, stream>>>(Pbw, Qbw, rsw, adj, wmrw);
    k_mn <<<(int)(RN / 2), 256, 0, stream>>>(slots, Ptw, Qw, wmrw, ge, bge,
                                             XWw, WCw, vw, bn1, gn, bgn, Wn2, bn2, out);
}